// Round 6
// baseline (144.643 us; speedup 1.0000x reference)
//
#include <hip/hip_runtime.h>
#include <math.h>

// Problem: B=1, H=2, S=128, D=64, 2D=128, D*D=4096
// out[h,j,d] = sum_e ( sum_c Hbar[h,j,c]*W2[c, d*64+e] + b2[d*64+e] ) * K[h,j,e]
// Hbar[h,j,c] = (1/S) * sum_i tanh( A[h,i,c] + Bm[h,j,c] + b1[c] )
// A[h,i,c]  = sum_d Q[h,i,d] * W1[d,    c]
// Bm[h,j,c] = sum_e K[h,j,e] * W1[64+e, c]
//
// Single kernel, NO cross-block dependency: block = (h, cset8, jset16).
// Each block computes A/Bm/tanh for its (cset,jset) locally (tanh is
// partitioned exactly -> zero redundancy), the partial c-sum of the W2
// contraction, and atomicAdds its contribution into out (16 adds/element).

#define H_ 2
#define S_ 128
#define D_ 64
#define C_ 128  // 2D

// fast tanh: 1 - 2/(exp(2x)+1). v_exp_f32 + v_rcp_f32, ~1e-6 abs error,
// saturates correctly at +/-1.
__device__ __forceinline__ float ftanh(float x) {
    float e2 = __expf(2.0f * x);
    return 1.0f - 2.0f * __builtin_amdgcn_rcpf(e2 + 1.0f);
}

__global__ __launch_bounds__(256, 1) void fused(
    const float* __restrict__ Q, const float* __restrict__ K,
    const float* __restrict__ W1, const float* __restrict__ b1,
    const float* __restrict__ W2, const float* __restrict__ b2,
    float* __restrict__ out)
{
    const int b  = blockIdx.x;      // h(1b) | cs(4b) | js(3b)
    const int h  = b >> 7;
    const int cs = (b >> 3) & 15;   // this block's 8 c's: [cs*8, cs*8+8)
    const int js = b & 7;           // this block's 16 j's: [js*16, js*16+16)
    const int tid  = threadIdx.x;
    const int lane = tid & 63;
    const int w    = tid >> 6;      // wave 0..3 (uniform)

    // ---- Prefetch phase-C operands; latency overlaps phases A/B ----
    // w2reg[c2*16+dd] = W2[cs*8+c2, (w*16+dd)*64 + lane]  (coalesced 256B/instr)
    float w2reg[128];
#pragma unroll
    for (int c2 = 0; c2 < 8; ++c2)
#pragma unroll
        for (int dd = 0; dd < 16; ++dd)
            w2reg[c2*16 + dd] = W2[(cs*8 + c2)*4096 + (w*16 + dd)*64 + lane];

    float kv[16];                   // K[h, js*16+j, lane]
#pragma unroll
    for (int j = 0; j < 16; ++j)
        kv[j] = K[(h*S_ + js*16 + j)*D_ + lane];

    float b2v[16];                  // b2 added by cs==0 blocks only
#pragma unroll
    for (int dd = 0; dd < 16; ++dd)
        b2v[dd] = (cs == 0) ? b2[(w*16 + dd)*64 + lane] : 0.f;

    __shared__ float As[S_*8];      // A[i][c'], stride 8
    __shared__ float Bs[16*8];      // Bm[j][c'] + b1[c]
    __shared__ float Hs[16*8];      // Hbar[j][c']
    __shared__ float red[256];

    // ---- Phase A1: A[i, c'] for all 128 i, this block's 8 c ----
    {
        const int i  = tid & 127;
        const int cp = tid >> 7;            // 0/1 (wave-uniform)
        const int cbase = cs*8 + cp*4;
        const float4* __restrict__ qrow = (const float4*)(Q + (h*S_ + i)*D_);
        float a0 = 0.f, a1 = 0.f, a2 = 0.f, a3 = 0.f;
#pragma unroll
        for (int d4 = 0; d4 < 16; ++d4) {
            const float4 q = qrow[d4];
            const float* __restrict__ r0 = W1 + (4*d4 + 0)*C_ + cbase;  // uniform -> s_load_dwordx4
            const float* __restrict__ r1 = W1 + (4*d4 + 1)*C_ + cbase;
            const float* __restrict__ r2 = W1 + (4*d4 + 2)*C_ + cbase;
            const float* __restrict__ r3 = W1 + (4*d4 + 3)*C_ + cbase;
            a0 += q.x*r0[0] + q.y*r1[0] + q.z*r2[0] + q.w*r3[0];
            a1 += q.x*r0[1] + q.y*r1[1] + q.z*r2[1] + q.w*r3[1];
            a2 += q.x*r0[2] + q.y*r1[2] + q.z*r2[2] + q.w*r3[2];
            a3 += q.x*r0[3] + q.y*r1[3] + q.z*r2[3] + q.w*r3[3];
        }
        *(float4*)&As[i*8 + cp*4] = make_float4(a0, a1, a2, a3);
    }

    // ---- Phase A2: Bs[j][c'] = K-row . W1-bottom-col + b1 ----
    if (tid < 128) {
        const int j  = tid >> 3;
        const int c2 = tid & 7;
        const int cg = cs*8 + c2;
        const float4* __restrict__ kr = (const float4*)(K + (h*S_ + js*16 + j)*D_);
        float acc = b1[cg];
#pragma unroll
        for (int d4 = 0; d4 < 16; ++d4) {
            const float4 kq = kr[d4];
            acc += kq.x * W1[(64 + 4*d4 + 0)*C_ + cg]
                 + kq.y * W1[(64 + 4*d4 + 1)*C_ + cg]
                 + kq.z * W1[(64 + 4*d4 + 2)*C_ + cg]
                 + kq.w * W1[(64 + 4*d4 + 3)*C_ + cg];
        }
        Bs[tid] = acc;              // tid == j*8 + c2
    }
    __syncthreads();

    // ---- Phase B: Hbar[j,c'] = mean_i tanh(As[i,c'] + Bs[j,c']) ----
    {
        const int jc = tid & 127;   // j*8 + c'
        const int c2 = jc & 7;
        const int half = tid >> 7;
        const float t = Bs[jc];
        float acc = 0.f;
#pragma unroll 8
        for (int i = half*64; i < half*64 + 64; ++i)
            acc += ftanh(As[i*8 + c2] + t);   // As: 8-addr broadcast, conflict-free
        red[tid] = acc;
    }
    __syncthreads();
    if (tid < 128)
        Hs[tid] = (red[tid] + red[tid + 128]) * (1.0f/128.f);
    __syncthreads();

    // ---- Phase C: partial Wh = sum_{c in cset} Hbar*W2; dot K; atomicAdd ----
    for (int j = 0; j < 16; ++j) {
        float hsv[8];
#pragma unroll
        for (int c2 = 0; c2 < 8; ++c2)
            hsv[c2] = Hs[j*8 + c2];           // same addr across wave: broadcast

        float acc[16];
#pragma unroll
        for (int dd = 0; dd < 16; ++dd) acc[dd] = b2v[dd];
#pragma unroll
        for (int c2 = 0; c2 < 8; ++c2)
#pragma unroll
            for (int dd = 0; dd < 16; ++dd)
                acc[dd] += hsv[c2] * w2reg[c2*16 + dd];

        const float kj = kv[j];
#pragma unroll
        for (int dd = 0; dd < 16; ++dd) {
            float v = acc[dd] * kj;
#pragma unroll
            for (int off = 32; off > 0; off >>= 1)
                v += __shfl_down(v, off);
            if (lane == 0)
                atomicAdd(&out[h*S_*D_ + (js*16 + j)*D_ + (w*16 + dd)], v);
        }
    }
}

extern "C" void kernel_launch(void* const* d_in, const int* in_sizes, int n_in,
                              void* d_out, int out_size, void* d_ws, size_t ws_size,
                              hipStream_t stream) {
    const float* Q  = (const float*)d_in[0];   // [1,2,128,64]
    const float* K  = (const float*)d_in[1];   // [1,2,128,64]
    const float* W1 = (const float*)d_in[2];   // [128,128]
    const float* b1 = (const float*)d_in[3];   // [128]
    const float* W2 = (const float*)d_in[4];   // [128,4096]
    const float* b2 = (const float*)d_in[5];   // [4096]
    float* out = (float*)d_out;                // [1,2,128,64]

    // out accumulates via atomics; harness poisons it to 0xAA -> zero it.
    hipMemsetAsync(out, 0, (size_t)out_size * sizeof(float), stream);
    fused<<<256, 256, 0, stream>>>(Q, K, W1, b1, W2, b2, out);
}

// Round 7
// 86.074 us; speedup vs baseline: 1.6805x; 1.6805x over previous
//
#include <hip/hip_runtime.h>
#include <hip/hip_bf16.h>
#include <math.h>

// Problem: B=1, H=2, S=128, D=64, 2D=128, D*D=4096
// out[h,j,d] = sum_e ( sum_c Hbar[h,j,c]*W2[c, d*64+e] + b2[d*64+e] ) * K[h,j,e]
// Hbar[h,j,c] = (1/S) * sum_i tanh( A[h,i,c] + Bm[h,j,c] + b1[c] )
// A[h,i,c]  = sum_d Q[h,i,d] * W1[d,    c]
// Bm[h,j,c] = sum_e K[h,j,e] * W1[64+e, c]

#define H_ 2
#define S_ 128
#define D_ 64
#define C_ 128  // 2D

// fast tanh: 1 - 2/(exp(2x)+1). v_exp_f32 + v_rcp_f32, ~1e-6 abs error.
// Saturates correctly at +/-1 for large |x|.
__device__ __forceinline__ float ftanh(float x) {
    float e2 = __expf(2.0f * x);
    return 1.0f - 2.0f * __builtin_amdgcn_rcpf(e2 + 1.0f);
}

// ---------------- Kernel 1+2 fused: Hbar, decomposed by (h, c) ----------------
// Block b = (h, c). The block computes the full column A[h,:,c], Bm[h,:,c]+b1[c]
// into LDS (no global A/Bm at all), then the 128x128 tanh-mean for column c.
// W1 column reads are block-uniform -> scalar pipe; As reads are LDS broadcast.
__global__ __launch_bounds__(256) void k12_hbar(const float* __restrict__ Q,
                                                const float* __restrict__ K,
                                                const float* __restrict__ W1,
                                                const float* __restrict__ b1,
                                                float* __restrict__ Hbar) {
    const int b = blockIdx.x;          // h*128 + c
    const int h = b >> 7;
    const int c = b & 127;
    const int tid = threadIdx.x;

    __shared__ float As[S_];           // A[h, i, c]
    __shared__ float Bs[S_];           // Bm[h, j, c] + b1[c]
    __shared__ float red[256];

    // Step 1: waves 0-1 compute As (from Q), waves 2-3 compute Bs (from K).
    {
        const int r   = tid & 127;     // i (sel=0) or j (sel=1)
        const int sel = tid >> 7;      // wave-uniform
        const float* __restrict__ src = sel ? K : Q;
        const float* __restrict__ w1col = W1 + sel*64*C_ + c;  // W1[sel*64+d][c]
        const float4* __restrict__ row = (const float4*)(src + (h*S_ + r)*D_);
        float acc = 0.f;
#pragma unroll
        for (int d4 = 0; d4 < D_/4; ++d4) {
            const float4 v = row[d4];
            acc += v.x * w1col[(4*d4 + 0)*C_]
                 + v.y * w1col[(4*d4 + 1)*C_]
                 + v.z * w1col[(4*d4 + 2)*C_]
                 + v.w * w1col[(4*d4 + 3)*C_];
        }
        if (sel == 0) As[r] = acc;
        else          Bs[r] = acc + b1[c];
    }
    __syncthreads();

    // Step 2: thread (j, q) sums tanh over its 64 i's. As[i] is an LDS
    // broadcast (same address across the wave) -> conflict-free.
    {
        const int j = tid & 127, q = tid >> 7;
        const float t = Bs[j];
        const float* __restrict__ Aq = As + q*64;
        float acc = 0.f;
#pragma unroll 8
        for (int i = 0; i < 64; ++i)
            acc += ftanh(Aq[i] + t);
        red[tid] = acc;
    }
    __syncthreads();

    if (tid < 128) {
        Hbar[(h*S_ + tid)*C_ + c] = (red[tid] + red[tid + 128]) * (1.0f/128.f);
    }
}

// ---------------- Kernel 3: fused W2 contraction + K-dot ----------------
// grid: H*D*4 = 512 blocks -> (h, d, j-quarter). 256 threads = 4 waves; lane=e.
// Wave w handles 8 j's. 2 blocks/CU (launch_bounds 256,2) so the 128-deep
// W2 prefetch of one block overlaps the FMA phase of the other. W2 column
// slice lives in VGPRs; Hbar rows are wave-uniform -> scalar loads; no LDS
// in the main loop. Shuffle reductions deferred to the epilogue.
__global__ __launch_bounds__(256, 2) void k3_out(const float* __restrict__ K,
                                                 const float* __restrict__ W2,
                                                 const float* __restrict__ b2,
                                                 const float* __restrict__ Hbar,
                                                 float* __restrict__ out) {
    const int b = blockIdx.x;          // 0..511
    const int h  = b >> 8;
    const int d  = (b >> 2) & 63;
    const int jq = b & 3;
    const int lane = threadIdx.x & 63;     // e
    const int w = __builtin_amdgcn_readfirstlane(threadIdx.x >> 6);
    const int jbase = jq*32 + w*8;

    // W2 column slice for this (d, e): 128 floats in VGPRs, coalesced loads.
    float w2reg[C_];
#pragma unroll
    for (int c = 0; c < C_; ++c) {
        w2reg[c] = W2[c*4096 + d*64 + lane];
    }

    // K values for this lane's e across the wave's 8 j's.
    float kv[8];
#pragma unroll
    for (int jj = 0; jj < 8; ++jj) {
        kv[jj] = K[(h*S_ + jbase + jj)*D_ + lane];
    }
    const float b2v = b2[d*64 + lane];

    // Main loop: uniform Hbar rows (scalar pipe) + VALU only.
    const float* __restrict__ Hbase = Hbar + (h*S_ + jbase)*C_;
    float acc[8];
#pragma unroll
    for (int jj = 0; jj < 8; ++jj) {
        const float* __restrict__ Hrow = Hbase + jj*C_;  // wave-uniform
        float t0 = 0.f, t1 = 0.f, t2 = 0.f, t3 = 0.f;
#pragma unroll
        for (int c = 0; c < C_; c += 4) {
            t0 += Hrow[c + 0] * w2reg[c + 0];
            t1 += Hrow[c + 1] * w2reg[c + 1];
            t2 += Hrow[c + 2] * w2reg[c + 2];
            t3 += Hrow[c + 3] * w2reg[c + 3];
        }
        acc[jj] = (t0 + t1) + (t2 + t3);
    }

    // Epilogue: (acc + b2)*K, reduce over e (64 lanes), write out.
#pragma unroll
    for (int jj = 0; jj < 8; ++jj) {
        float v = (acc[jj] + b2v) * kv[jj];
#pragma unroll
        for (int off = 32; off > 0; off >>= 1)
            v += __shfl_down(v, off);
        if (lane == 0)
            out[h*S_*D_ + (jbase + jj)*D_ + d] = v;
    }
}

extern "C" void kernel_launch(void* const* d_in, const int* in_sizes, int n_in,
                              void* d_out, int out_size, void* d_ws, size_t ws_size,
                              hipStream_t stream) {
    const float* Q  = (const float*)d_in[0];   // [1,2,128,64]
    const float* K  = (const float*)d_in[1];   // [1,2,128,64]
    const float* W1 = (const float*)d_in[2];   // [128,128]
    const float* b1 = (const float*)d_in[3];   // [128]
    const float* W2 = (const float*)d_in[4];   // [128,4096]
    const float* b2 = (const float*)d_in[5];   // [4096]
    float* out = (float*)d_out;                // [1,2,128,64]

    float* Hbar = (float*)d_ws;                // [2,128,128]

    k12_hbar<<<H_*S_,   256, 0, stream>>>(Q, K, W1, b1, Hbar);
    k3_out  <<<H_*D_*4, 256, 0, stream>>>(K, W2, b2, Hbar, out);
}

// Round 8
// 85.793 us; speedup vs baseline: 1.6860x; 1.0033x over previous
//
#include <hip/hip_runtime.h>
#include <hip/hip_bf16.h>
#include <math.h>

// Problem: B=1, H=2, S=128, D=64, 2D=128, D*D=4096
// out[h,j,d] = sum_e ( sum_c Hbar[h,j,c]*W2[c, d*64+e] + b2[d*64+e] ) * K[h,j,e]
// Hbar[h,j,c] = (1/S) * sum_i tanh( A[h,i,c] + Bm[h,j,c] + b1[c] )
// A[h,i,c]  = sum_d Q[h,i,d] * W1[d,    c]
// Bm[h,j,c] = sum_e K[h,j,e] * W1[64+e, c]

#define H_ 2
#define S_ 128
#define D_ 64
#define C_ 128  // 2D

// fast tanh: 1 - 2/(exp(2x)+1). v_exp_f32 + v_rcp_f32, ~1e-6 abs error.
// Saturates correctly at +/-1 for large |x|.
__device__ __forceinline__ float ftanh(float x) {
    float e2 = __expf(2.0f * x);
    return 1.0f - 2.0f * __builtin_amdgcn_rcpf(e2 + 1.0f);
}

// ---------------- Kernel 1+2 fused: Hbar, decomposed by (h, j-half, c) --------
// Block b = (h, jh, c): 512 blocks -> 2 blocks/CU so prefetch/compute of one
// block overlaps the other. Block recomputes the full A column (cheap, 2x
// redundant) but Bs/tanh are exactly partitioned. c is block-uniform -> W1
// column reads ride the scalar pipe; As reads are LDS broadcasts.
__global__ __launch_bounds__(256, 2) void k12_hbar(const float* __restrict__ Q,
                                                   const float* __restrict__ K,
                                                   const float* __restrict__ W1,
                                                   const float* __restrict__ b1,
                                                   float* __restrict__ Hbar) {
    const int b  = blockIdx.x;         // h(1b) | jh(1b) | c(7b)
    const int h  = b >> 8;
    const int jh = (b >> 7) & 1;
    const int c  = b & 127;
    const int tid = threadIdx.x;

    __shared__ float As[S_];           // A[h, i, c], all 128 i
    __shared__ float Bs[64];           // Bm[h, jh*64 + j, c] + b1[c]
    __shared__ float red[256];

    // Step 1: waves 0-1 compute As (128 rows from Q); wave 2 computes Bs
    // (64 rows from K); wave 3 has no staging work.
    {
        const int r   = tid & 127;
        const int sel = tid >> 7;      // wave-uniform: 0 -> As, 1 -> Bs
        if (sel == 0 || r < 64) {
            const int row = (sel == 0) ? r : (jh*64 + r);
            const float* __restrict__ src = sel ? K : Q;
            const float* __restrict__ w1col = W1 + sel*64*C_ + c;  // uniform col
            const float4* __restrict__ rw = (const float4*)(src + (h*S_ + row)*D_);
            float acc = 0.f;
#pragma unroll
            for (int d4 = 0; d4 < D_/4; ++d4) {
                const float4 v = rw[d4];
                acc += v.x * w1col[(4*d4 + 0)*C_]
                     + v.y * w1col[(4*d4 + 1)*C_]
                     + v.z * w1col[(4*d4 + 2)*C_]
                     + v.w * w1col[(4*d4 + 3)*C_];
            }
            if (sel == 0) As[r] = acc;
            else          Bs[r] = acc + b1[c];
        }
    }
    __syncthreads();

    // Step 2: thread (j, q) sums tanh over its 32 i's. As[i] is an LDS
    // broadcast (same address across the wave) -> conflict-free.
    {
        const int j = tid & 63, q = tid >> 6;   // q = i-quarter (wave-uniform)
        const float t = Bs[j];
        const float* __restrict__ Aq = As + q*32;
        float acc = 0.f;
#pragma unroll 8
        for (int i = 0; i < 32; ++i)
            acc += ftanh(Aq[i] + t);
        red[tid] = acc;
    }
    __syncthreads();

    if (tid < 64) {
        Hbar[(h*S_ + jh*64 + tid)*C_ + c] =
            (red[tid] + red[tid + 64] + red[tid + 128] + red[tid + 192])
            * (1.0f/128.f);
    }
}

// ---------------- Kernel 3: fused W2 contraction + K-dot ----------------
// grid: H*D*4 = 512 blocks -> (h, d, j-quarter). 256 threads = 4 waves; lane=e.
// Wave w handles 8 j's. 2 blocks/CU (launch_bounds 256,2) so the 128-deep
// W2 prefetch of one block overlaps the FMA phase of the other. W2 column
// slice lives in VGPRs; Hbar rows are wave-uniform -> scalar loads; no LDS
// in the main loop. Shuffle reductions deferred to the epilogue.
__global__ __launch_bounds__(256, 2) void k3_out(const float* __restrict__ K,
                                                 const float* __restrict__ W2,
                                                 const float* __restrict__ b2,
                                                 const float* __restrict__ Hbar,
                                                 float* __restrict__ out) {
    const int b = blockIdx.x;          // 0..511
    const int h  = b >> 8;
    const int d  = (b >> 2) & 63;
    const int jq = b & 3;
    const int lane = threadIdx.x & 63;     // e
    const int w = __builtin_amdgcn_readfirstlane(threadIdx.x >> 6);
    const int jbase = jq*32 + w*8;

    // W2 column slice for this (d, e): 128 floats in VGPRs, coalesced loads.
    float w2reg[C_];
#pragma unroll
    for (int c = 0; c < C_; ++c) {
        w2reg[c] = W2[c*4096 + d*64 + lane];
    }

    // K values for this lane's e across the wave's 8 j's.
    float kv[8];
#pragma unroll
    for (int jj = 0; jj < 8; ++jj) {
        kv[jj] = K[(h*S_ + jbase + jj)*D_ + lane];
    }
    const float b2v = b2[d*64 + lane];

    // Main loop: uniform Hbar rows (scalar pipe) + VALU only.
    const float* __restrict__ Hbase = Hbar + (h*S_ + jbase)*C_;
    float acc[8];
#pragma unroll
    for (int jj = 0; jj < 8; ++jj) {
        const float* __restrict__ Hrow = Hbase + jj*C_;  // wave-uniform
        float t0 = 0.f, t1 = 0.f, t2 = 0.f, t3 = 0.f;
#pragma unroll
        for (int c = 0; c < C_; c += 4) {
            t0 += Hrow[c + 0] * w2reg[c + 0];
            t1 += Hrow[c + 1] * w2reg[c + 1];
            t2 += Hrow[c + 2] * w2reg[c + 2];
            t3 += Hrow[c + 3] * w2reg[c + 3];
        }
        acc[jj] = (t0 + t1) + (t2 + t3);
    }

    // Epilogue: (acc + b2)*K, reduce over e (64 lanes), write out.
#pragma unroll
    for (int jj = 0; jj < 8; ++jj) {
        float v = (acc[jj] + b2v) * kv[jj];
#pragma unroll
        for (int off = 32; off > 0; off >>= 1)
            v += __shfl_down(v, off);
        if (lane == 0)
            out[h*S_*D_ + (jbase + jj)*D_ + d] = v;
    }
}

extern "C" void kernel_launch(void* const* d_in, const int* in_sizes, int n_in,
                              void* d_out, int out_size, void* d_ws, size_t ws_size,
                              hipStream_t stream) {
    const float* Q  = (const float*)d_in[0];   // [1,2,128,64]
    const float* K  = (const float*)d_in[1];   // [1,2,128,64]
    const float* W1 = (const float*)d_in[2];   // [128,128]
    const float* b1 = (const float*)d_in[3];   // [128]
    const float* W2 = (const float*)d_in[4];   // [128,4096]
    const float* b2 = (const float*)d_in[5];   // [4096]
    float* out = (float*)d_out;                // [1,2,128,64]

    float* Hbar = (float*)d_ws;                // [2,128,128]

    k12_hbar<<<H_*S_*2, 256, 0, stream>>>(Q, K, W1, b1, Hbar);
    k3_out  <<<H_*D_*4, 256, 0, stream>>>(K, W2, b2, Hbar, out);
}